// Round 15
// baseline (100.467 us; speedup 1.0000x reference)
//
#include <hip/hip_runtime.h>
#include <math.h>

#define N_ 32
#define C_ 256
#define H_ 56
#define W_ 56
#define HW_ (H_*W_)          // 3136
#define HW4_ (HW_/4)         // 784
#define CHW_ (C_*HW_)        // 802816
#define CHW4_ (CHW_/4)       // 200704
#define NHW_ (N_*HW_)        // 100352
#define NHW4_ (NHW_/4)       // 25088
#define NCW_ (N_*C_*W_)      // 458752
#define NHC_ (N_*H_*C_)      // 458752
#define BN_EPS_ 1e-5f

#define TLD 57               // odd LDS stride: col & row scalar chains conflict-free

#define F4MAX(a,b) do { (a).x=fmaxf((a).x,(b).x); (a).y=fmaxf((a).y,(b).y); \
                        (a).z=fmaxf((a).z,(b).z); (a).w=fmaxf((a).w,(b).w); } while(0)
#define F4ADD(a,b) do { (a).x+=(b).x; (a).y+=(b).y; (a).z+=(b).z; (a).w+=(b).w; } while(0)

// ---- plane pools: 1 wave = 1 plane, zero barriers, no serial plane chain ----
// Produces maxH/meanH [n,c,w], maxWt/meanWt [n,c,h] (transposed storage), y[n,c].
__global__ __launch_bounds__(64) void plane_k(
        const float* __restrict__ x,
        float* __restrict__ maxH, float* __restrict__ meanH,
        float* __restrict__ maxWt, float* __restrict__ meanWt,
        float* __restrict__ y) {
    __shared__ float tile[H_ * TLD];               // 12768 B
    const int wid = blockIdx.x;                    // plane id 0..8191
    const int lane = threadIdx.x;
    const int n = wid >> 8, c = wid & 255;
    const float4* x4 = (const float4*)x + (size_t)wid * HW4_;

    // coalesced load of the whole plane (13 f4 per lane; last chunk 16 lanes)
    float4 r[12], rl;
    #pragma unroll
    for (int i = 0; i < 12; ++i) r[i] = x4[i * 64 + lane];
    if (lane < 16) rl = x4[768 + lane];
    // scatter into padded tile (scalar writes; consecutive within each f4)
    #pragma unroll
    for (int i = 0; i < 12; ++i) {
        int u = i * 64 + lane;
        int row = u / 14, c0 = (u - row * 14) * 4;
        float* d = &tile[row * TLD + c0];
        d[0] = r[i].x; d[1] = r[i].y; d[2] = r[i].z; d[3] = r[i].w;
    }
    if (lane < 16) {
        int u = 768 + lane;
        int row = u / 14, c0 = (u - row * 14) * 4;
        float* d = &tile[row * TLD + c0];
        d[0] = rl.x; d[1] = rl.y; d[2] = rl.z; d[3] = rl.w;
    }
    // col phase: lane = w; consecutive LDS addresses per step -> conflict-free
    float csm = 0.f;
    if (lane < W_) {
        float cmx = -INFINITY;
        #pragma unroll 8
        for (int j = 0; j < H_; ++j) {
            float v = tile[j * TLD + lane];
            cmx = fmaxf(cmx, v); csm += v;
        }
        int o = (n * C_ + c) * W_ + lane;
        maxH[o] = cmx;
        meanH[o] = csm * (1.f / H_);
    }
    // y[n,c] via full-wave shuffle of column sums
    float ysum = (lane < W_) ? csm : 0.f;
    #pragma unroll
    for (int off = 32; off >= 1; off >>= 1) ysum += __shfl_xor(ysum, off);
    if (lane == 0) y[n * C_ + c] = ysum * (1.f / HW_);
    // row phase: lane = h; stride-57 rows (odd) -> conflict-free scalar chain
    if (lane < H_) {
        const float* rp = &tile[lane * TLD];
        float rmx = -INFINITY, rsm = 0.f;
        #pragma unroll 8
        for (int j = 0; j < W_; ++j) {
            float v = rp[j];
            rmx = fmaxf(rmx, v); rsm += v;
        }
        int o = (n * C_ + c) * H_ + lane;          // transposed, coalesced
        maxWt[o] = rmx;
        meanWt[o] = rsm * (1.f / W_);
    }
}

// ---- C-pool standalone: direct maxC/meanC, no partials sideband ----
// 784 blocks x 256: thread (g=tid>>5 chains 32 channels, qi=tid&31 -> f4 out)
__global__ __launch_bounds__(256) void cpool_k(
        const float* __restrict__ x,
        float* __restrict__ maxC, float* __restrict__ meanC) {
    __shared__ float4 smx[256];
    __shared__ float4 ssm[256];
    int bb = blockIdx.x;
    int tid = threadIdx.x;
    int g = tid >> 5, qi = tid & 31;
    int q = bb * 32 + qi;                          // 0..NHW4-1
    int n = q / HW4_;
    int hw4 = q - n * HW4_;
    const float4* x4 = (const float4*)x;
    size_t base = (size_t)n * CHW4_ + hw4 + (size_t)(g * 32) * HW4_;
    float4 mx = make_float4(-INFINITY, -INFINITY, -INFINITY, -INFINITY);
    float4 sm = make_float4(0.f, 0.f, 0.f, 0.f);
    #pragma unroll 16
    for (int i = 0; i < 32; ++i) {
        float4 v = x4[base + (size_t)i * HW4_];
        F4MAX(mx, v);
        F4ADD(sm, v);
    }
    smx[g * 32 + qi] = mx;
    ssm[g * 32 + qi] = sm;
    __syncthreads();
    if (tid < 32) {
        float4 m = smx[tid];
        #pragma unroll
        for (int j = 1; j < 8; ++j) F4MAX(m, smx[j * 32 + tid]);
        ((float4*)maxC)[bb * 32 + tid] = m;
    } else if (tid < 64) {
        int t2 = tid - 32;
        float4 s = ssm[t2];
        #pragma unroll
        for (int j = 1; j < 8; ++j) F4ADD(s, ssm[j * 32 + t2]);
        s.x *= (1.f / C_); s.y *= (1.f / C_); s.z *= (1.f / C_); s.w *= (1.f / C_);
        ((float4*)meanC)[bb * 32 + t2] = s;
    }
}

// ---- conv 7x7 + BN + sigmoid; TR=true uses transposed kernel weights ----
template <int R, int Cc, bool TR>
__device__ __forceinline__ void conv7_part(int t, const float* __restrict__ p0,
                                           const float* __restrict__ p1,
                                           const float* __restrict__ wt,
                                           float g, float bb, float m, float v,
                                           float* __restrict__ out) {
    const int per = R * Cc;
    int n = t / per;
    int r2 = t - n * per;
    int i = r2 / Cc, j = r2 - i * Cc;
    const float* b0 = p0 + (size_t)n * per;
    const float* b1 = p1 + (size_t)n * per;
    float acc = 0.f;
    #pragma unroll
    for (int ki = 0; ki < 7; ++ki) {
        int ii = i + ki - 3;
        if (ii < 0 || ii >= R) continue;
        #pragma unroll
        for (int kj = 0; kj < 7; ++kj) {
            int jj = j + kj - 3;
            if (jj < 0 || jj >= Cc) continue;
            int idx = ii * Cc + jj;
            int wi = TR ? (kj * 7 + ki) : (ki * 7 + kj);
            acc += b0[idx] * wt[wi] + b1[idx] * wt[49 + wi];
        }
    }
    float o = (acc - m) * rsqrtf(v + BN_EPS_) * g + bb;
    out[t] = 1.f / (1.f + expf(-o));
}

#define NB_SS (NHW_ / 256)            // 392
#define NB_SH (NCW_ / 256)            // 1792
#define NB_SW (NHC_ / 256)            // 1792

// ---- fused: 3 gate convs + ECA sort/conv/unsort ----
__global__ __launch_bounds__(256) void conv_eca_k(
        const float* __restrict__ maxC, const float* __restrict__ meanC,
        const float* __restrict__ maxH, const float* __restrict__ meanH,
        const float* __restrict__ maxWt, const float* __restrict__ meanWt,
        const float* __restrict__ w_s, const float* __restrict__ g_s,
        const float* __restrict__ b_s, const float* __restrict__ m_s,
        const float* __restrict__ v_s,
        const float* __restrict__ w_h, const float* __restrict__ g_h,
        const float* __restrict__ b_h, const float* __restrict__ m_h,
        const float* __restrict__ v_h,
        const float* __restrict__ w_w, const float* __restrict__ g_w,
        const float* __restrict__ b_w, const float* __restrict__ m_w,
        const float* __restrict__ v_w,
        const float* __restrict__ y, const float* __restrict__ w_eca,
        float* __restrict__ s_s, float* __restrict__ s_h, float* __restrict__ s_wt,
        float* __restrict__ gate) {
    __shared__ float sv[C_];
    __shared__ int si[C_];
    int b = blockIdx.x;
    int tid = threadIdx.x;
    if (b < NB_SS) {
        conv7_part<H_, W_, false>(b * 256 + tid, maxC, meanC, w_s, g_s[0], b_s[0],
                                  m_s[0], v_s[0], s_s);
    } else if (b < NB_SS + NB_SH) {
        conv7_part<C_, W_, false>((b - NB_SS) * 256 + tid, maxH, meanH, w_h, g_h[0],
                                  b_h[0], m_h[0], v_h[0], s_h);
    } else if (b < NB_SS + NB_SH + NB_SW) {
        conv7_part<C_, H_, true>((b - NB_SS - NB_SH) * 256 + tid, maxWt, meanWt, w_w,
                                 g_w[0], b_w[0], m_w[0], v_w[0], s_wt);
    } else {
        int n = b - (NB_SS + NB_SH + NB_SW);
        sv[tid] = y[n * C_ + tid];
        si[tid] = tid;
        __syncthreads();
        for (int k = 2; k <= C_; k <<= 1) {
            for (int j = k >> 1; j > 0; j >>= 1) {
                int ixj = tid ^ j;
                if (ixj > tid) {
                    float v1 = sv[tid], v2 = sv[ixj];
                    int i1 = si[tid], i2 = si[ixj];
                    bool before = (v1 > v2) || (v1 == v2 && i1 < i2);
                    bool dir = ((tid & k) == 0);
                    if (dir ? !before : before) {
                        sv[tid] = v2; sv[ixj] = v1;
                        si[tid] = i2; si[ixj] = i1;
                    }
                }
                __syncthreads();
            }
        }
        float o = 0.f;
        #pragma unroll
        for (int j = 0; j < 5; ++j) {
            int p = tid + j - 2;
            if (p >= 0 && p < C_) o += sv[p] * w_eca[j];
        }
        gate[n * C_ + si[tid]] = 1.f / (1.f + expf(-o));
    }
}

// ---- final apply: 2 float4 per thread; s_wt read transposed ----
__global__ __launch_bounds__(256) void apply_k(
        const float* __restrict__ x, const float* __restrict__ s_s,
        const float* __restrict__ s_h, const float* __restrict__ s_wt,
        const float* __restrict__ gate, float* __restrict__ out) {
    int t0 = blockIdx.x * 512 + threadIdx.x;
    #pragma unroll
    for (int r = 0; r < 2; ++r) {
        int t = t0 + r * 256;
        int f = t * 4;
        int n = f / CHW_;
        int rem = f - n * CHW_;
        int c = rem / HW_;
        int hw = rem - c * HW_;
        int h = hw / W_;
        int w = hw - h * W_;
        float4 xv = ((const float4*)x)[t];
        float4 s4 = *(const float4*)(s_s + (size_t)n * HW_ + hw);
        float4 h4 = *(const float4*)(s_h + ((size_t)n * C_ + c) * W_ + w);
        float sw = s_wt[((size_t)n * C_ + c) * H_ + h];
        float ge = gate[n * C_ + c];
        float base = 0.24365f * sw + 0.27173f * ge;
        float4 o;
        o.x = xv.x * (0.23779f * s4.x + 0.24695f * h4.x + base);
        o.y = xv.y * (0.23779f * s4.y + 0.24695f * h4.y + base);
        o.z = xv.z * (0.23779f * s4.z + 0.24695f * h4.z + base);
        o.w = xv.w * (0.23779f * s4.w + 0.24695f * h4.w + base);
        ((float4*)out)[t] = o;
    }
}

extern "C" void kernel_launch(void* const* d_in, const int* in_sizes, int n_in,
                              void* d_out, int out_size, void* d_ws, size_t ws_size,
                              hipStream_t stream) {
    const float* x     = (const float*)d_in[0];
    const float* w_h   = (const float*)d_in[2];
    const float* g_h   = (const float*)d_in[3];
    const float* b_h   = (const float*)d_in[4];
    const float* m_h   = (const float*)d_in[5];
    const float* v_h   = (const float*)d_in[6];
    const float* w_w   = (const float*)d_in[7];
    const float* g_w   = (const float*)d_in[8];
    const float* b_w   = (const float*)d_in[9];
    const float* m_w   = (const float*)d_in[10];
    const float* v_w   = (const float*)d_in[11];
    const float* w_s   = (const float*)d_in[12];
    const float* g_s   = (const float*)d_in[13];
    const float* b_s   = (const float*)d_in[14];
    const float* m_s   = (const float*)d_in[15];
    const float* v_s   = (const float*)d_in[16];
    const float* w_eca = (const float*)d_in[17];
    float* out = (float*)d_out;

    float* ws    = (float*)d_ws;
    float* maxC  = ws;                  // NHW
    float* meanC = maxC  + NHW_;        // NHW
    float* maxH  = meanC + NHW_;        // NCW
    float* meanH = maxH  + NCW_;        // NCW
    float* maxWt = meanH + NCW_;        // NHC (stored [n][c][h])
    float* meanWt= maxWt + NHC_;        // NHC
    float* s_s   = meanWt+ NHC_;        // NHW
    float* s_h   = s_s   + NHW_;        // NCW
    float* s_wt  = s_h   + NCW_;        // NHC (stored [n][c][h])
    float* yv    = s_wt  + NHC_;        // N*C
    float* gate  = yv    + N_ * C_;     // N*C

    plane_k<<<N_ * C_, 64, 0, stream>>>(x, maxH, meanH, maxWt, meanWt, yv);

    cpool_k<<<NHW4_ / 32, 256, 0, stream>>>(x, maxC, meanC);

    int conv_blocks = NB_SS + NB_SH + NB_SW + N_;
    conv_eca_k<<<conv_blocks, 256, 0, stream>>>(maxC, meanC, maxH, meanH, maxWt, meanWt,
                                                w_s, g_s, b_s, m_s, v_s,
                                                w_h, g_h, b_h, m_h, v_h,
                                                w_w, g_w, b_w, m_w, v_w,
                                                yv, w_eca, s_s, s_h, s_wt, gate);

    apply_k<<<(N_ * CHW_ / 4) / 512, 256, 0, stream>>>(x, s_s, s_h, s_wt, gate, out);
}